// Round 4
// baseline (470.608 us; speedup 1.0000x reference)
//
#include <hip/hip_runtime.h>
#include <hip/hip_bf16.h>

// Problem constants (match reference)
#define N_NODES 50000
#define N_EDGES 800000
#define IN_C 256
#define HID_C 128
#define OUT_C 64

#define NB_SCAN ((N_NODES + 255) / 256)   // 196 blocks of 256 nodes

typedef __attribute__((ext_vector_type(8))) short bf16x8;
typedef __attribute__((ext_vector_type(4))) float f32x4;

__device__ __forceinline__ ushort f2bf(float f) {
    uint u = __float_as_uint(f);
    u += 0x7fff + ((u >> 16) & 1);   // round-to-nearest-even
    return (ushort)(u >> 16);
}
__device__ __forceinline__ float bf2f(ushort h) {
    return __uint_as_float(((uint)h) << 16);
}

// ---------------------------------------------------------------------------
// Graph preprocessing
// ---------------------------------------------------------------------------

__global__ __launch_bounds__(256) void init_deg_kernel(int* __restrict__ degi) {
    int i = blockIdx.x * 256 + threadIdx.x;
    if (i < N_NODES) degi[i] = 1;  // self-loop
}

__global__ __launch_bounds__(256) void count_deg_kernel(const int* __restrict__ dst,
                                                        int* __restrict__ degi) {
    int e = blockIdx.x * 256 + threadIdx.x;
    if (e < N_EDGES) atomicAdd(&degi[dst[e]], 1);
}

__global__ __launch_bounds__(256) void deg_partial_kernel(const int* __restrict__ degi,
                                                          int* __restrict__ partials) {
    __shared__ int s[256];
    int t = threadIdx.x;
    int i = blockIdx.x * 256 + t;
    s[t] = (i < N_NODES) ? degi[i] : 0;
    __syncthreads();
#pragma unroll
    for (int off = 128; off > 0; off >>= 1) {
        if (t < off) s[t] += s[t + off];
        __syncthreads();
    }
    if (t == 0) partials[blockIdx.x] = s[0];
}

__global__ __launch_bounds__(256) void scan_partials_kernel(const int* __restrict__ partials,
                                                            int* __restrict__ partial_off,
                                                            int* __restrict__ row_ptr) {
    __shared__ int s[256];
    int t = threadIdx.x;
    s[t] = (t < NB_SCAN) ? partials[t] : 0;
    __syncthreads();
#pragma unroll
    for (int off = 1; off < 256; off <<= 1) {
        int x = s[t];
        int add = (t >= off) ? s[t - off] : 0;
        __syncthreads();
        s[t] = x + add;
        __syncthreads();
    }
    if (t < NB_SCAN) partial_off[t] = (t == 0) ? 0 : s[t - 1];
    if (t == 255) row_ptr[N_NODES] = s[255];
}

__global__ __launch_bounds__(256) void scan_final_kernel(const int* __restrict__ degi,
                                                         const int* __restrict__ partial_off,
                                                         int* __restrict__ row_ptr,
                                                         int* __restrict__ cursor,
                                                         float* __restrict__ dis) {
    __shared__ int s[256];
    int t = threadIdx.x;
    int i = blockIdx.x * 256 + t;
    int d = (i < N_NODES) ? degi[i] : 0;
    s[t] = d;
    __syncthreads();
#pragma unroll
    for (int off = 1; off < 256; off <<= 1) {
        int x = s[t];
        int add = (t >= off) ? s[t - off] : 0;
        __syncthreads();
        s[t] = x + add;
        __syncthreads();
    }
    if (i < N_NODES) {
        int excl = partial_off[blockIdx.x] + s[t] - d;
        row_ptr[i] = excl;
        cursor[i] = excl;
        dis[i] = rsqrtf((float)d);
    }
}

// 4B scatter per edge: src index only (norm is factorized via dis)
__global__ __launch_bounds__(256) void scatter_kernel(const int* __restrict__ src,
                                                      const int* __restrict__ dst,
                                                      int* __restrict__ cursor,
                                                      int* __restrict__ csr_src) {
    int i = blockIdx.x * 256 + threadIdx.x;
    if (i >= N_EDGES + N_NODES) return;
    int s, d;
    if (i < N_EDGES) {
        s = src[i];
        d = dst[i];
    } else {
        s = d = i - N_EDGES;
    }
    int slot = atomicAdd(&cursor[d], 1);
    csr_src[slot] = s;
}

// ---------------------------------------------------------------------------
// Weight packing: W[K][N] fp32 -> fragment-ordered bf16 hi/lo
// layout: Pk[kt][ct][lane][j], element = W[kt*32 + (lane>>4)*8 + j][ct*16 + (lane&15)]
// ---------------------------------------------------------------------------

__global__ __launch_bounds__(64) void pack_w_kernel(const float* __restrict__ W,
                                                    ushort* __restrict__ Ph,
                                                    ushort* __restrict__ Pl,
                                                    int K, int N) {
    int lane = threadIdx.x;
    int CT = N / 16;
    int ct = blockIdx.x % CT;
    int kt = blockIdx.x / CT;
    int lr = lane & 15, lg = lane >> 4;
    size_t base = ((size_t)blockIdx.x * 64 + lane) * 8;
#pragma unroll
    for (int j = 0; j < 8; j++) {
        float w = W[(size_t)(kt * 32 + lg * 8 + j) * N + ct * 16 + lr];
        ushort h = f2bf(w);
        ushort lo = f2bf(w - bf2f(h));
        Ph[base + j] = h;
        Pl[base + j] = lo;
    }
}

// ---------------------------------------------------------------------------
// LDS-free MFMA GEMM with 3-term bf16 split.
// C[M][N] = A[M][K] @ W[K][N]. Wave owns 32 rows x N cols; block = 128 rows.
// OUT_MODE: 0 = fp32 + bias (row-major), 1 = bf16 hi/lo + bias (row-major),
//           2 = fp32 * dis[row], SLICE-MAJOR layout gs[ct][M][16]
// ---------------------------------------------------------------------------

template <int K, int N, int OUT_MODE, bool AF32>
__global__ __launch_bounds__(256) void gemm_mfma_kernel(
    const float* __restrict__ Af, const ushort* __restrict__ Ahi,
    const ushort* __restrict__ Alo, const ushort* __restrict__ Wph,
    const ushort* __restrict__ Wpl, const float* __restrict__ bias,
    const float* __restrict__ disp, float* __restrict__ Cf,
    ushort* __restrict__ CHi, ushort* __restrict__ CLo, int M) {
    constexpr int CT = N / 16;
    constexpr int KT = K / 32;

    const int wid = threadIdx.x >> 6;
    const int lane = threadIdx.x & 63;
    const int lr = lane & 15;
    const int lg = lane >> 4;
    const int row_base = blockIdx.x * 128 + wid * 32;

    f32x4 acc[2][CT];
#pragma unroll
    for (int rt = 0; rt < 2; rt++)
#pragma unroll
        for (int ct = 0; ct < CT; ct++) acc[rt][ct] = (f32x4){0.f, 0.f, 0.f, 0.f};

    for (int kt = 0; kt < KT; kt++) {
        const int kof = kt * 32 + lg * 8;
        bf16x8 ah[2], al[2];
#pragma unroll
        for (int rt = 0; rt < 2; rt++) {
            int r = row_base + rt * 16 + lr;
            if (r >= M) r = M - 1;  // clamp; result discarded on store
            if (AF32) {
                const float* ap = &Af[(size_t)r * K + kof];
                float4 v0 = *(const float4*)ap;
                float4 v1 = *(const float4*)(ap + 4);
                float av[8] = {v0.x, v0.y, v0.z, v0.w, v1.x, v1.y, v1.z, v1.w};
#pragma unroll
                for (int j = 0; j < 8; j++) {
                    ushort h = f2bf(av[j]);
                    ushort lo = f2bf(av[j] - bf2f(h));
                    ah[rt][j] = (short)h;
                    al[rt][j] = (short)lo;
                }
            } else {
                ah[rt] = *(const bf16x8*)&Ahi[(size_t)r * K + kof];
                al[rt] = *(const bf16x8*)&Alo[(size_t)r * K + kof];
            }
        }
        const ushort* bh = &Wph[(size_t)kt * CT * 512 + (size_t)lane * 8];
        const ushort* bl = &Wpl[(size_t)kt * CT * 512 + (size_t)lane * 8];
#pragma unroll
        for (int ct = 0; ct < CT; ct++) {
            bf16x8 bhv = *(const bf16x8*)(bh + ct * 512);
            bf16x8 blv = *(const bf16x8*)(bl + ct * 512);
#pragma unroll
            for (int rt = 0; rt < 2; rt++) {
                acc[rt][ct] = __builtin_amdgcn_mfma_f32_16x16x32_bf16(ah[rt], bhv, acc[rt][ct], 0, 0, 0);
                acc[rt][ct] = __builtin_amdgcn_mfma_f32_16x16x32_bf16(al[rt], bhv, acc[rt][ct], 0, 0, 0);
                acc[rt][ct] = __builtin_amdgcn_mfma_f32_16x16x32_bf16(ah[rt], blv, acc[rt][ct], 0, 0, 0);
            }
        }
    }

    // Epilogue: D[row][col], row = rt*16 + lg*4 + j, col = ct*16 + lr
#pragma unroll
    for (int rt = 0; rt < 2; rt++)
#pragma unroll
        for (int ct = 0; ct < CT; ct++)
#pragma unroll
            for (int j = 0; j < 4; j++) {
                int r = row_base + rt * 16 + lg * 4 + j;
                if (r >= M) continue;
                int c = ct * 16 + lr;
                float v = acc[rt][ct][j];
                if (OUT_MODE == 2) {
                    // slice-major: gs[ct][r][lr], scaled by dis[r]
                    Cf[(size_t)ct * M * 16 + (size_t)r * 16 + lr] = v * disp[r];
                } else {
                    v += bias[c];
                    if (OUT_MODE == 1) {
                        ushort h = f2bf(v);
                        ushort lo = f2bf(v - bf2f(h));
                        CHi[(size_t)r * N + c] = h;
                        CLo[(size_t)r * N + c] = lo;
                    } else {
                        Cf[(size_t)r * N + c] = v;
                    }
                }
            }
}

// ---------------------------------------------------------------------------
// XCD-sliced CSR aggregation.
// g is slice-major [8][N][16] (each slice 3.2 MB, L2-resident per XCD).
// Block = 256 thr = 16 nodes x 16 channels; slice = blockIdx.x % 8 -> XCD.
// out = relu(dis[node] * sum_e g[src[e]] + bias) -> bf16 hi/lo (row-major).
// ---------------------------------------------------------------------------

__global__ __launch_bounds__(256) void aggregate_kernel(const float* __restrict__ gs,
                                                        const int* __restrict__ row_ptr,
                                                        const int* __restrict__ csr_src,
                                                        const float* __restrict__ dis,
                                                        const float* __restrict__ bias,
                                                        ushort* __restrict__ Hi,
                                                        ushort* __restrict__ Lo) {
    const int slice = blockIdx.x & 7;
    const int nb = blockIdx.x >> 3;
    const int ty = threadIdx.x >> 4;
    const int tx = threadIdx.x & 15;
    const int node = nb * 16 + ty;
    const float* __restrict__ g = gs + (size_t)slice * N_NODES * 16;

    const int s0 = row_ptr[node];
    const int s1 = row_ptr[node + 1];

    float a = 0.f;
    int e = s0;
    for (; e + 4 <= s1; e += 4) {
        int i0 = csr_src[e + 0];
        int i1 = csr_src[e + 1];
        int i2 = csr_src[e + 2];
        int i3 = csr_src[e + 3];
        float v0 = g[i0 * 16 + tx];
        float v1 = g[i1 * 16 + tx];
        float v2 = g[i2 * 16 + tx];
        float v3 = g[i3 * 16 + tx];
        a += (v0 + v1) + (v2 + v3);
    }
    for (; e < s1; e++) a += g[csr_src[e] * 16 + tx];

    const int ch = slice * 16 + tx;
    float v = fmaxf(dis[node] * a + bias[ch], 0.f);
    ushort h = f2bf(v);
    ushort l = f2bf(v - bf2f(h));
    Hi[(size_t)node * HID_C + ch] = h;
    Lo[(size_t)node * HID_C + ch] = l;
}

// ---------------------------------------------------------------------------
// Launch
// ---------------------------------------------------------------------------

extern "C" void kernel_launch(void* const* d_in, const int* in_sizes, int n_in,
                              void* d_out, int out_size, void* d_ws, size_t ws_size,
                              hipStream_t stream) {
    const float* x       = (const float*)d_in[0];
    const int*   eidx    = (const int*)d_in[1];
    const float* proj_W  = (const float*)d_in[2];
    const float* proj_b  = (const float*)d_in[3];
    const float* conv_W0 = (const float*)d_in[4];
    const float* conv_b0 = (const float*)d_in[5];
    const float* conv_W1 = (const float*)d_in[6];
    const float* conv_b1 = (const float*)d_in[7];
    const float* conv_W2 = (const float*)d_in[8];
    const float* conv_b2 = (const float*)d_in[9];
    const float* out_W   = (const float*)d_in[10];
    const float* out_b   = (const float*)d_in[11];
    float* out = (float*)d_out;

    const int* src = eidx;
    const int* dst = eidx + N_EDGES;

    char* ws = (char*)d_ws;
    size_t off = 0;
    auto carve = [&](size_t bytes) {
        void* p = ws + off;
        off += (bytes + 255) & ~(size_t)255;
        return p;
    };
    int*   degi     = (int*)carve(N_NODES * sizeof(int));
    int*   row_ptr  = (int*)carve((N_NODES + 1) * sizeof(int));
    int*   cursor   = (int*)carve(N_NODES * sizeof(int));
    int*   csr_src  = (int*)carve((size_t)(N_EDGES + N_NODES) * sizeof(int));
    float* dis      = (float*)carve(N_NODES * sizeof(float));
    int*   partials = (int*)carve(NB_SCAN * sizeof(int));
    int*   poff     = (int*)carve(NB_SCAN * sizeof(int));
    ushort* projPh = (ushort*)carve((size_t)IN_C * HID_C * sizeof(ushort));
    ushort* projPl = (ushort*)carve((size_t)IN_C * HID_C * sizeof(ushort));
    ushort* convPh[3], *convPl[3];
    for (int l = 0; l < 3; l++) {
        convPh[l] = (ushort*)carve((size_t)HID_C * HID_C * sizeof(ushort));
        convPl[l] = (ushort*)carve((size_t)HID_C * HID_C * sizeof(ushort));
    }
    ushort* outPh = (ushort*)carve((size_t)HID_C * OUT_C * sizeof(ushort));
    ushort* outPl = (ushort*)carve((size_t)HID_C * OUT_C * sizeof(ushort));
    ushort* hHi = (ushort*)carve((size_t)N_NODES * HID_C * sizeof(ushort));
    ushort* hLo = (ushort*)carve((size_t)N_NODES * HID_C * sizeof(ushort));
    float*  g   = (float*)carve((size_t)N_NODES * HID_C * sizeof(float));  // slice-major

    // Graph preprocessing
    init_deg_kernel<<<NB_SCAN, 256, 0, stream>>>(degi);
    count_deg_kernel<<<(N_EDGES + 255) / 256, 256, 0, stream>>>(dst, degi);
    deg_partial_kernel<<<NB_SCAN, 256, 0, stream>>>(degi, partials);
    scan_partials_kernel<<<1, 256, 0, stream>>>(partials, poff, row_ptr);
    scan_final_kernel<<<NB_SCAN, 256, 0, stream>>>(degi, poff, row_ptr, cursor, dis);
    scatter_kernel<<<(N_EDGES + N_NODES + 255) / 256, 256, 0, stream>>>(
        src, dst, cursor, csr_src);

    // Weight packing
    pack_w_kernel<<<(IN_C / 32) * (HID_C / 16), 64, 0, stream>>>(proj_W, projPh, projPl, IN_C, HID_C);
    pack_w_kernel<<<(HID_C / 32) * (HID_C / 16), 64, 0, stream>>>(conv_W0, convPh[0], convPl[0], HID_C, HID_C);
    pack_w_kernel<<<(HID_C / 32) * (HID_C / 16), 64, 0, stream>>>(conv_W1, convPh[1], convPl[1], HID_C, HID_C);
    pack_w_kernel<<<(HID_C / 32) * (HID_C / 16), 64, 0, stream>>>(conv_W2, convPh[2], convPl[2], HID_C, HID_C);
    pack_w_kernel<<<(HID_C / 32) * (OUT_C / 16), 64, 0, stream>>>(out_W, outPh, outPl, HID_C, OUT_C);

    const int gemm_grid = (N_NODES + 127) / 128;  // 391
    const int agg_grid = (N_NODES / 16) * 8;      // 25000

    // Projection: h = x @ proj_W + proj_b  -> hi/lo
    gemm_mfma_kernel<IN_C, HID_C, 1, true><<<gemm_grid, 256, 0, stream>>>(
        x, nullptr, nullptr, projPh, projPl, proj_b, nullptr, nullptr, hHi, hLo, N_NODES);

    // 3 GCN layers
    ushort* Wh_[3] = {convPh[0], convPh[1], convPh[2]};
    ushort* Wl_[3] = {convPl[0], convPl[1], convPl[2]};
    const float* bs_[3] = {conv_b0, conv_b1, conv_b2};
    for (int l = 0; l < 3; l++) {
        // g[slice][node][16] = dis[node] * (h @ W)[node]
        gemm_mfma_kernel<HID_C, HID_C, 2, false><<<gemm_grid, 256, 0, stream>>>(
            nullptr, hHi, hLo, Wh_[l], Wl_[l], nullptr, dis, g, nullptr, nullptr, N_NODES);
        aggregate_kernel<<<agg_grid, 256, 0, stream>>>(
            g, row_ptr, csr_src, dis, bs_[l], hHi, hLo);
    }

    // Output: out = h @ out_W + out_b (fp32)
    gemm_mfma_kernel<HID_C, OUT_C, 0, false><<<gemm_grid, 256, 0, stream>>>(
        nullptr, hHi, hLo, outPh, outPl, out_b, nullptr, out, nullptr, nullptr, N_NODES);
}